// Round 1
// baseline (5789.091 us; speedup 1.0000x reference)
//
#include <hip/hip_runtime.h>

#define WALK 16
#define HID 64

// ---------------------------------------------------------------------------
// ws layout: deg[N] | dinv[N] | probs[(WALK+1)*N]   (planar: plane k = prob
// after k steps; plane 0 = ones). Total 19*N*4 = 7.6 MB.
// ---------------------------------------------------------------------------

__global__ __launch_bounds__(256) void init_kernel(float* __restrict__ deg,
                                                   float* __restrict__ probs,
                                                   int N) {
    int i = blockIdx.x * 256 + threadIdx.x;
    if (i < N) {
        deg[i]   = 1.0f;   // self-loop weight 1 pre-added
        probs[i] = 1.0f;   // plane 0 = init ones
        #pragma unroll
        for (int k = 1; k <= WALK; ++k) probs[(size_t)k * N + i] = 0.0f;
    }
}

__global__ __launch_bounds__(256) void deg_kernel(const int* __restrict__ row,
                                                  const float* __restrict__ ew,
                                                  float* __restrict__ deg, int E) {
    int e = blockIdx.x * 256 + threadIdx.x;
    if (e < E) atomicAdd(&deg[row[e]], ew[e]);
}

__global__ __launch_bounds__(256) void inv_kernel(const float* __restrict__ deg,
                                                  float* __restrict__ dinv, int N) {
    int i = blockIdx.x * 256 + threadIdx.x;
    if (i < N) dinv[i] = 1.0f / fmaxf(deg[i], 1e-8f);
}

// one step: dst[col] += src[row] * ew * dinv[row]  (+ self loop w=1)
__global__ __launch_bounds__(256) void step_kernel(const int* __restrict__ ei,
                                                   const float* __restrict__ ew,
                                                   const float* __restrict__ dinv,
                                                   const float* __restrict__ src,
                                                   float* __restrict__ dst,
                                                   int E, int N) {
    int idx = blockIdx.x * 256 + threadIdx.x;
    if (idx < E) {
        int r = ei[idx];          // edge_index[0][e]
        int c = ei[E + idx];      // edge_index[1][e]
        float v = src[r] * ew[idx] * dinv[r];
        atomicAdd(&dst[c], v);
    } else if (idx < E + N) {
        int i = idx - E;          // self loop, weight 1
        atomicAdd(&dst[i], src[i] * dinv[i]);
    }
}

// per-node MLP: out = W2 @ relu(W1 @ rwpe + b1) + b2
__global__ __launch_bounds__(256) void mlp_kernel(const float* __restrict__ probs,
                                                  const float* __restrict__ W1,
                                                  const float* __restrict__ b1,
                                                  const float* __restrict__ W2,
                                                  const float* __restrict__ b2,
                                                  float* __restrict__ out, int N) {
    __shared__ float W1s[HID * WALK];
    __shared__ float W2s[HID * HID];
    __shared__ float b1s[HID], b2s[HID];
    int tid = threadIdx.x;
    for (int i = tid; i < HID * WALK; i += 256) W1s[i] = W1[i];
    for (int i = tid; i < HID * HID; i += 256) W2s[i] = W2[i];
    if (tid < HID) { b1s[tid] = b1[tid]; b2s[tid] = b2[tid]; }
    __syncthreads();

    int n = blockIdx.x * 256 + tid;
    if (n >= N) return;

    float p[WALK];
    #pragma unroll
    for (int k = 0; k < WALK; ++k) p[k] = probs[(size_t)(k + 1) * N + n]; // coalesced planar reads

    float h[HID];
    #pragma unroll
    for (int j = 0; j < HID; ++j) {
        float a = b1s[j];
        #pragma unroll
        for (int k = 0; k < WALK; ++k) a += W1s[j * WALK + k] * p[k];
        h[j] = fmaxf(a, 0.0f);
    }

    #pragma unroll
    for (int j = 0; j < HID; j += 4) {
        float4 o;
        float* op = (float*)&o;
        #pragma unroll
        for (int q = 0; q < 4; ++q) {
            float a = b2s[(j + q)];
            #pragma unroll
            for (int k = 0; k < HID; ++k) a += W2s[(j + q) * HID + k] * h[k];
            op[q] = a;
        }
        *(float4*)&out[(size_t)n * HID + j] = o;
    }
}

extern "C" void kernel_launch(void* const* d_in, const int* in_sizes, int n_in,
                              void* d_out, int out_size, void* d_ws, size_t ws_size,
                              hipStream_t stream) {
    // inputs: 0 edge_index(2E i32) 1 num_nodes 2 edge_weight(E f32)
    //         3 W1(64x16) 4 b1(64) 5 W2(64x64) 6 b2(64)
    const int*   ei = (const int*)d_in[0];
    const float* ew = (const float*)d_in[2];
    const float* W1 = (const float*)d_in[3];
    const float* b1 = (const float*)d_in[4];
    const float* W2 = (const float*)d_in[5];
    const float* b2 = (const float*)d_in[6];
    const int E = in_sizes[2];
    const int N = out_size / HID;   // avoids device read of num_nodes

    float* deg   = (float*)d_ws;
    float* dinv  = deg + N;
    float* probs = dinv + N;        // (WALK+1) planes of N
    float* out   = (float*)d_out;

    init_kernel<<<(N + 255) / 256, 256, 0, stream>>>(deg, probs, N);
    deg_kernel<<<(E + 255) / 256, 256, 0, stream>>>(ei, ew, deg, E);
    inv_kernel<<<(N + 255) / 256, 256, 0, stream>>>(deg, dinv, N);
    for (int k = 0; k < WALK; ++k) {
        step_kernel<<<(E + N + 255) / 256, 256, 0, stream>>>(
            ei, ew, dinv, probs + (size_t)k * N, probs + (size_t)(k + 1) * N, E, N);
    }
    mlp_kernel<<<(N + 255) / 256, 256, 0, stream>>>(probs, W1, b1, W2, b2, out, N);
}

// Round 2
// 1848.179 us; speedup vs baseline: 3.1323x; 3.1323x over previous
//
#include <hip/hip_runtime.h>

#define WALK 16
#define HID 64

// ===========================================================================
// Fast path (needs ~60 MB ws): build col-CSR once, then 16 pull-gather steps
// with zero atomics. Fallback path (ws too small): R1 push-atomic version.
//
// ws layout (fast path), 4B units:
//   csr    : 2E   (uint2 {row, ew_bits}, at base for 8B alignment)
//   rowptr : N+1
//   wp     : N    (doubles as cnt during histogram)
//   bsum   : 1024
//   deg    : N
//   dinv   : N
//   qA     : N
//   qB     : N
//   probs  : 16N  (plane k = prob after step k+1)
// ===========================================================================

// ---------------- fast path kernels ----------------

__global__ __launch_bounds__(256) void init_fast(int* __restrict__ cnt,
                                                 float* __restrict__ deg, int N) {
    int i = blockIdx.x * 256 + threadIdx.x;
    if (i < N) { cnt[i] = 0; deg[i] = 1.0f; }   // self-loop weight pre-added
}

__global__ __launch_bounds__(256) void hist_kernel(const int* __restrict__ ei,
                                                   const float* __restrict__ ew,
                                                   int* __restrict__ cnt,
                                                   float* __restrict__ deg, int E) {
    int e = blockIdx.x * 256 + threadIdx.x;
    if (e < E) {
        atomicAdd(&cnt[ei[E + e]], 1);      // count incoming edges per col
        atomicAdd(&deg[ei[e]], ew[e]);      // weighted out-degree per row
    }
}

// block-level exclusive scan (chunk = 1024)
__global__ __launch_bounds__(1024) void scan_a(const int* __restrict__ cnt,
                                               int* __restrict__ excl,
                                               int* __restrict__ bsum, int N) {
    int tid = threadIdx.x, gid = blockIdx.x * 1024 + tid;
    int x = (gid < N) ? cnt[gid] : 0;
    int lane = tid & 63, wid = tid >> 6;
    int v = x;
    #pragma unroll
    for (int d = 1; d < 64; d <<= 1) { int t = __shfl_up(v, d); if (lane >= d) v += t; }
    __shared__ int wsum[16];
    if (lane == 63) wsum[wid] = v;
    __syncthreads();
    if (tid < 16) {
        int s = wsum[tid];
        #pragma unroll
        for (int d = 1; d < 16; d <<= 1) { int t = __shfl_up(s, d); if (tid >= d) s += t; }
        wsum[tid] = s;
    }
    __syncthreads();
    int woff = wid ? wsum[wid - 1] : 0;
    if (gid < N) excl[gid] = woff + v - x;
    if (tid == 0) bsum[blockIdx.x] = wsum[15];
}

// single-block exclusive scan of block sums (nb <= 1024)
__global__ __launch_bounds__(1024) void scan_b(int* __restrict__ bsum, int nb) {
    int tid = threadIdx.x;
    int x = (tid < nb) ? bsum[tid] : 0;
    int lane = tid & 63, wid = tid >> 6;
    int v = x;
    #pragma unroll
    for (int d = 1; d < 64; d <<= 1) { int t = __shfl_up(v, d); if (lane >= d) v += t; }
    __shared__ int wsum[16];
    if (lane == 63) wsum[wid] = v;
    __syncthreads();
    if (tid < 16) {
        int s = wsum[tid];
        #pragma unroll
        for (int d = 1; d < 16; d <<= 1) { int t = __shfl_up(s, d); if (tid >= d) s += t; }
        wsum[tid] = s;
    }
    __syncthreads();
    int woff = wid ? wsum[wid - 1] : 0;
    if (tid < nb) bsum[tid] = woff + v - x;
}

__global__ __launch_bounds__(1024) void scan_c(int* __restrict__ rowptr,
                                               int* __restrict__ wp,
                                               const int* __restrict__ bsum,
                                               int N, int E) {
    int gid = blockIdx.x * 1024 + threadIdx.x;
    if (gid < N) {
        int v = rowptr[gid] + bsum[blockIdx.x];
        rowptr[gid] = v;
        wp[gid] = v;
    }
    if (gid == 0) rowptr[N] = E;
}

__global__ __launch_bounds__(256) void inv_fast(const float* __restrict__ deg,
                                                float* __restrict__ dinv,
                                                float* __restrict__ q0, int N) {
    int i = blockIdx.x * 256 + threadIdx.x;
    if (i < N) {
        float dv = 1.0f / fmaxf(deg[i], 1e-8f);
        dinv[i] = dv;
        q0[i] = dv;           // q = prob * dinv, initial prob = 1
    }
}

__global__ __launch_bounds__(256) void scatter_kernel(const int* __restrict__ ei,
                                                      const float* __restrict__ ew,
                                                      int* __restrict__ wp,
                                                      uint2* __restrict__ csr, int E) {
    int e = blockIdx.x * 256 + threadIdx.x;
    if (e < E) {
        int c = ei[E + e];
        int pos = atomicAdd(&wp[c], 1);
        csr[pos] = make_uint2((unsigned)ei[e], __float_as_uint(ew[e]));
    }
}

// one step, pull-based: one wave per node, no atomics.
// prob_new[n] = sum_{incoming e} q[src_e]*w_e + q[n];  q_new = prob_new * dinv
__global__ __launch_bounds__(256) void step_pull(const int* __restrict__ rowptr,
                                                 const uint2* __restrict__ csr,
                                                 const float* __restrict__ q,
                                                 const float* __restrict__ dinv,
                                                 float* __restrict__ prob_out,
                                                 float* __restrict__ q_out, int N) {
    int gw = (blockIdx.x * 256 + threadIdx.x) >> 6;
    int lane = threadIdx.x & 63;
    if (gw >= N) return;
    int s = rowptr[gw], e = rowptr[gw + 1];
    float acc = 0.0f;
    for (int i = s + lane; i < e; i += 64) {
        uint2 t = csr[i];
        acc += q[t.x] * __uint_as_float(t.y);
    }
    #pragma unroll
    for (int d = 32; d > 0; d >>= 1) acc += __shfl_xor(acc, d);
    if (lane == 0) {
        float p = acc + q[gw];        // self loop: prob[n]*1*dinv[n] = q[n]
        prob_out[gw] = p;
        q_out[gw] = p * dinv[gw];
    }
}

// per-node MLP: out = W2 @ relu(W1 @ rwpe + b1) + b2
// probs plane k (k=0..15) = prob after step k+1
__global__ __launch_bounds__(256) void mlp_kernel(const float* __restrict__ probs,
                                                  const float* __restrict__ W1,
                                                  const float* __restrict__ b1,
                                                  const float* __restrict__ W2,
                                                  const float* __restrict__ b2,
                                                  float* __restrict__ out, int N) {
    __shared__ float W1s[HID * WALK];
    __shared__ float W2s[HID * HID];
    __shared__ float b1s[HID], b2s[HID];
    int tid = threadIdx.x;
    for (int i = tid; i < HID * WALK; i += 256) W1s[i] = W1[i];
    for (int i = tid; i < HID * HID; i += 256) W2s[i] = W2[i];
    if (tid < HID) { b1s[tid] = b1[tid]; b2s[tid] = b2[tid]; }
    __syncthreads();

    int n = blockIdx.x * 256 + tid;
    if (n >= N) return;

    float p[WALK];
    #pragma unroll
    for (int k = 0; k < WALK; ++k) p[k] = probs[(size_t)k * N + n];

    float h[HID];
    #pragma unroll
    for (int j = 0; j < HID; ++j) {
        float a = b1s[j];
        #pragma unroll
        for (int k = 0; k < WALK; ++k) a += W1s[j * WALK + k] * p[k];
        h[j] = fmaxf(a, 0.0f);
    }

    #pragma unroll
    for (int j = 0; j < HID; j += 4) {
        float4 o;
        float* op = (float*)&o;
        #pragma unroll
        for (int q = 0; q < 4; ++q) {
            float a = b2s[j + q];
            #pragma unroll
            for (int k = 0; k < HID; ++k) a += W2s[(j + q) * HID + k] * h[k];
            op[q] = a;
        }
        *(float4*)&out[(size_t)n * HID + j] = o;
    }
}

// ---------------- fallback (R1 push) kernels ----------------

__global__ __launch_bounds__(256) void init_push(float* __restrict__ deg,
                                                 float* __restrict__ probs, int N) {
    int i = blockIdx.x * 256 + threadIdx.x;
    if (i < N) {
        deg[i] = 1.0f;
        probs[i] = 1.0f;
        #pragma unroll
        for (int k = 1; k <= WALK; ++k) probs[(size_t)k * N + i] = 0.0f;
    }
}

__global__ __launch_bounds__(256) void deg_push(const int* __restrict__ row,
                                                const float* __restrict__ ew,
                                                float* __restrict__ deg, int E) {
    int e = blockIdx.x * 256 + threadIdx.x;
    if (e < E) atomicAdd(&deg[row[e]], ew[e]);
}

__global__ __launch_bounds__(256) void inv_push(const float* __restrict__ deg,
                                                float* __restrict__ dinv, int N) {
    int i = blockIdx.x * 256 + threadIdx.x;
    if (i < N) dinv[i] = 1.0f / fmaxf(deg[i], 1e-8f);
}

__global__ __launch_bounds__(256) void step_push(const int* __restrict__ ei,
                                                 const float* __restrict__ ew,
                                                 const float* __restrict__ dinv,
                                                 const float* __restrict__ src,
                                                 float* __restrict__ dst,
                                                 int E, int N) {
    int idx = blockIdx.x * 256 + threadIdx.x;
    if (idx < E) {
        int r = ei[idx], c = ei[E + idx];
        atomicAdd(&dst[c], src[r] * ew[idx] * dinv[r]);
    } else if (idx < E + N) {
        int i = idx - E;
        atomicAdd(&dst[i], src[i] * dinv[i]);
    }
}

__global__ __launch_bounds__(256) void mlp_push(const float* __restrict__ probs,
                                                const float* __restrict__ W1,
                                                const float* __restrict__ b1,
                                                const float* __restrict__ W2,
                                                const float* __restrict__ b2,
                                                float* __restrict__ out, int N) {
    __shared__ float W1s[HID * WALK];
    __shared__ float W2s[HID * HID];
    __shared__ float b1s[HID], b2s[HID];
    int tid = threadIdx.x;
    for (int i = tid; i < HID * WALK; i += 256) W1s[i] = W1[i];
    for (int i = tid; i < HID * HID; i += 256) W2s[i] = W2[i];
    if (tid < HID) { b1s[tid] = b1[tid]; b2s[tid] = b2[tid]; }
    __syncthreads();
    int n = blockIdx.x * 256 + tid;
    if (n >= N) return;
    float p[WALK];
    #pragma unroll
    for (int k = 0; k < WALK; ++k) p[k] = probs[(size_t)(k + 1) * N + n];
    float h[HID];
    #pragma unroll
    for (int j = 0; j < HID; ++j) {
        float a = b1s[j];
        #pragma unroll
        for (int k = 0; k < WALK; ++k) a += W1s[j * WALK + k] * p[k];
        h[j] = fmaxf(a, 0.0f);
    }
    #pragma unroll
    for (int j = 0; j < HID; j += 4) {
        float4 o;
        float* op = (float*)&o;
        #pragma unroll
        for (int q = 0; q < 4; ++q) {
            float a = b2s[j + q];
            #pragma unroll
            for (int k = 0; k < HID; ++k) a += W2s[(j + q) * HID + k] * h[k];
            op[q] = a;
        }
        *(float4*)&out[(size_t)n * HID + j] = o;
    }
}

// ---------------- launch ----------------

extern "C" void kernel_launch(void* const* d_in, const int* in_sizes, int n_in,
                              void* d_out, int out_size, void* d_ws, size_t ws_size,
                              hipStream_t stream) {
    const int*   ei = (const int*)d_in[0];
    const float* ew = (const float*)d_in[2];
    const float* W1 = (const float*)d_in[3];
    const float* b1 = (const float*)d_in[4];
    const float* W2 = (const float*)d_in[5];
    const float* b2 = (const float*)d_in[6];
    const int E = in_sizes[2];
    const int N = out_size / HID;
    float* out = (float*)d_out;

    const int NB = (N + 255) / 256;

    size_t need = ((size_t)2 * E + 21 * (size_t)N + 1024 + 8) * 4;
    if (ws_size >= need) {
        // ---- fast path: col-CSR + pull steps ----
        char* p = (char*)d_ws;
        uint2* csr   = (uint2*)p;            p += (size_t)E * 8;
        int*  rowptr = (int*)p;              p += (size_t)(N + 1) * 4;
        int*  wp     = (int*)p;              p += (size_t)N * 4;
        int*  bsum   = (int*)p;              p += 1024 * 4;
        float* deg   = (float*)p;            p += (size_t)N * 4;
        float* dinv  = (float*)p;            p += (size_t)N * 4;
        float* qA    = (float*)p;            p += (size_t)N * 4;
        float* qB    = (float*)p;            p += (size_t)N * 4;
        float* probs = (float*)p;

        const int NBE = (E + 255) / 256;
        const int NC  = (N + 1023) / 1024;   // scan chunks (<= 1024)

        init_fast<<<NB, 256, 0, stream>>>(wp, deg, N);
        hist_kernel<<<NBE, 256, 0, stream>>>(ei, ew, wp, deg, E);
        scan_a<<<NC, 1024, 0, stream>>>(wp, rowptr, bsum, N);
        scan_b<<<1, 1024, 0, stream>>>(bsum, NC);
        scan_c<<<NC, 1024, 0, stream>>>(rowptr, wp, bsum, N, E);
        inv_fast<<<NB, 256, 0, stream>>>(deg, dinv, qA, N);
        scatter_kernel<<<NBE, 256, 0, stream>>>(ei, ew, wp, csr, E);

        const int NBW = (N * 64 + 255) / 256;   // one wave per node
        float* qs = qA; float* qd = qB;
        for (int k = 0; k < WALK; ++k) {
            step_pull<<<NBW, 256, 0, stream>>>(rowptr, csr, qs, dinv,
                                               probs + (size_t)k * N, qd, N);
            float* t = qs; qs = qd; qd = t;
        }
        mlp_kernel<<<NB, 256, 0, stream>>>(probs, W1, b1, W2, b2, out, N);
    } else {
        // ---- fallback: R1 push path ----
        float* deg   = (float*)d_ws;
        float* dinv  = deg + N;
        float* probs = dinv + N;
        init_push<<<NB, 256, 0, stream>>>(deg, probs, N);
        deg_push<<<(E + 255) / 256, 256, 0, stream>>>(ei, ew, deg, E);
        inv_push<<<NB, 256, 0, stream>>>(deg, dinv, N);
        for (int k = 0; k < WALK; ++k) {
            step_push<<<(E + N + 255) / 256, 256, 0, stream>>>(
                ei, ew, dinv, probs + (size_t)k * N, probs + (size_t)(k + 1) * N, E, N);
        }
        mlp_push<<<NB, 256, 0, stream>>>(probs, W1, b1, W2, b2, out, N);
    }
}

// Round 3
// 1832.028 us; speedup vs baseline: 3.1599x; 1.0088x over previous
//
#include <hip/hip_runtime.h>

#define WALK 16
#define HID 64
#define NXCD 8

// ===========================================================================
// Pull-gather RWPE with XCD-local replicated atomics for the CSR build.
//
// Device-scope atomics execute at the Infinity Fabric (~20 G/s wall, R1/R2
// measured). Workgroup-scope atomics compile to global_atomic without sc1 and
// execute in the issuing XCD's L2. We replicate the histogram / degree /
// write-pointer arrays 8x (one per XCD, selected by HW_REG_XCC_ID), so every
// atomic is XCD-local; replicas are reduced by later kernels (inter-kernel
// visibility via the HSA dispatch-boundary release/acquire).
//
// ws layout (4B units), fast path:
//   csr    : 2E        uint2 {row, ew_bits}
//   rowptr : N+1
//   wp     : N         (col totals for scan)
//   bsum   : 1024
//   dinv   : N
//   R      : 18N       = probs(16N) + qA(N) + qB(N)
//            overlay during build: cntx = R[0..8N) (int), degx = R[8N..16N)
//            (both dead before step 0 writes probs plane 0)
// need = (2E + 21N + 1024 + 32) * 4  — same as R2.
// ===========================================================================

__device__ __forceinline__ int xcd_id() {
    int x;
    asm volatile("s_getreg_b32 %0, hwreg(HW_REG_XCC_ID)" : "=s"(x));
    return x & (NXCD - 1);
}

__device__ __forceinline__ int wg_atomic_add(int* p, int v) {
    return __hip_atomic_fetch_add(p, v, __ATOMIC_RELAXED, __HIP_MEMORY_SCOPE_WORKGROUP);
}
__device__ __forceinline__ float wg_atomic_add(float* p, float v) {
    return __hip_atomic_fetch_add(p, v, __ATOMIC_RELAXED, __HIP_MEMORY_SCOPE_WORKGROUP);
}

// ---------------- build kernels ----------------

// per-edge: count col into this XCD's replica; accumulate weighted out-degree
__global__ __launch_bounds__(256) void hist2(const int* __restrict__ ei,
                                             const float* __restrict__ ew,
                                             int* __restrict__ cntx,
                                             float* __restrict__ degx,
                                             int N, int E) {
    int x = xcd_id();
    int e = blockIdx.x * 256 + threadIdx.x;
    if (e < E) {
        wg_atomic_add(&cntx[(size_t)x * N + ei[E + e]], 1);
        wg_atomic_add(&degx[(size_t)x * N + ei[e]], ew[e]);
    }
}

// reduce 8 replicas: col totals -> wp, deg -> dinv, q0 = 1*dinv
__global__ __launch_bounds__(256) void degred(const int* __restrict__ cntx,
                                              const float* __restrict__ degx,
                                              int* __restrict__ tot,
                                              float* __restrict__ dinv,
                                              float* __restrict__ q0, int N) {
    int n = blockIdx.x * 256 + threadIdx.x;
    if (n >= N) return;
    float d = 1.0f;   // self-loop weight
    int t = 0;
    #pragma unroll
    for (int x = 0; x < NXCD; ++x) {
        d += degx[(size_t)x * N + n];
        t += cntx[(size_t)x * N + n];
    }
    float dv = 1.0f / fmaxf(d, 1e-8f);
    dinv[n] = dv;
    q0[n] = dv;
    tot[n] = t;
}

// block-level exclusive scan (chunk = 1024)
__global__ __launch_bounds__(1024) void scan_a(const int* __restrict__ cnt,
                                               int* __restrict__ excl,
                                               int* __restrict__ bsum, int N) {
    int tid = threadIdx.x, gid = blockIdx.x * 1024 + tid;
    int x = (gid < N) ? cnt[gid] : 0;
    int lane = tid & 63, wid = tid >> 6;
    int v = x;
    #pragma unroll
    for (int d = 1; d < 64; d <<= 1) { int t = __shfl_up(v, d); if (lane >= d) v += t; }
    __shared__ int wsum[16];
    if (lane == 63) wsum[wid] = v;
    __syncthreads();
    if (tid < 16) {
        int s = wsum[tid];
        #pragma unroll
        for (int d = 1; d < 16; d <<= 1) { int t = __shfl_up(s, d); if (tid >= d) s += t; }
        wsum[tid] = s;
    }
    __syncthreads();
    int woff = wid ? wsum[wid - 1] : 0;
    if (gid < N) excl[gid] = woff + v - x;
    if (tid == 0) bsum[blockIdx.x] = wsum[15];
}

__global__ __launch_bounds__(1024) void scan_b(int* __restrict__ bsum, int nb) {
    int tid = threadIdx.x;
    int x = (tid < nb) ? bsum[tid] : 0;
    int lane = tid & 63, wid = tid >> 6;
    int v = x;
    #pragma unroll
    for (int d = 1; d < 64; d <<= 1) { int t = __shfl_up(v, d); if (lane >= d) v += t; }
    __shared__ int wsum[16];
    if (lane == 63) wsum[wid] = v;
    __syncthreads();
    if (tid < 16) {
        int s = wsum[tid];
        #pragma unroll
        for (int d = 1; d < 16; d <<= 1) { int t = __shfl_up(s, d); if (tid >= d) s += t; }
        wsum[tid] = s;
    }
    __syncthreads();
    int woff = wid ? wsum[wid - 1] : 0;
    if (tid < nb) bsum[tid] = woff + v - x;
}

// finish scan AND distribute per-(xcd,col) base write-pointers into cntx
__global__ __launch_bounds__(1024) void scan_c2(int* __restrict__ rowptr,
                                                int* __restrict__ cntx,
                                                const int* __restrict__ bsum,
                                                int N, int E) {
    int gid = blockIdx.x * 1024 + threadIdx.x;
    if (gid < N) {
        int v = rowptr[gid] + bsum[blockIdx.x];
        rowptr[gid] = v;
        int run = v;
        #pragma unroll
        for (int x = 0; x < NXCD; ++x) {
            int t = cntx[(size_t)x * N + gid];
            cntx[(size_t)x * N + gid] = run;   // base for this XCD's entries
            run += t;
        }
    }
    if (gid == 0) rowptr[N] = E;
}

// scatter edges into CSR buckets; position atomic is XCD-local
__global__ __launch_bounds__(256) void scatter2(const int* __restrict__ ei,
                                                const float* __restrict__ ew,
                                                int* __restrict__ cntx,
                                                uint2* __restrict__ csr,
                                                int N, int E) {
    int x = xcd_id();
    int e = blockIdx.x * 256 + threadIdx.x;
    if (e < E) {
        int c = ei[E + e];
        int pos = wg_atomic_add(&cntx[(size_t)x * N + c], 1);
        csr[pos] = make_uint2((unsigned)ei[e], __float_as_uint(ew[e]));
    }
}

// ---------------- propagation + MLP ----------------

// one step, pull-based: one wave per node, no atomics.
__global__ __launch_bounds__(256) void step_pull(const int* __restrict__ rowptr,
                                                 const uint2* __restrict__ csr,
                                                 const float* __restrict__ q,
                                                 const float* __restrict__ dinv,
                                                 float* __restrict__ prob_out,
                                                 float* __restrict__ q_out, int N) {
    int gw = (blockIdx.x * 256 + threadIdx.x) >> 6;
    int lane = threadIdx.x & 63;
    if (gw >= N) return;
    int s = rowptr[gw], e = rowptr[gw + 1];
    float acc = 0.0f;
    for (int i = s + lane; i < e; i += 64) {
        uint2 t = csr[i];
        acc += q[t.x] * __uint_as_float(t.y);
    }
    #pragma unroll
    for (int d = 32; d > 0; d >>= 1) acc += __shfl_xor(acc, d);
    if (lane == 0) {
        float p = acc + q[gw];   // self loop contribution
        prob_out[gw] = p;
        q_out[gw] = p * dinv[gw];
    }
}

__global__ __launch_bounds__(256) void mlp_kernel(const float* __restrict__ probs,
                                                  const float* __restrict__ W1,
                                                  const float* __restrict__ b1,
                                                  const float* __restrict__ W2,
                                                  const float* __restrict__ b2,
                                                  float* __restrict__ out, int N) {
    __shared__ float W1s[HID * WALK];
    __shared__ float W2s[HID * HID];
    __shared__ float b1s[HID], b2s[HID];
    int tid = threadIdx.x;
    for (int i = tid; i < HID * WALK; i += 256) W1s[i] = W1[i];
    for (int i = tid; i < HID * HID; i += 256) W2s[i] = W2[i];
    if (tid < HID) { b1s[tid] = b1[tid]; b2s[tid] = b2[tid]; }
    __syncthreads();

    int n = blockIdx.x * 256 + tid;
    if (n >= N) return;

    float p[WALK];
    #pragma unroll
    for (int k = 0; k < WALK; ++k) p[k] = probs[(size_t)k * N + n];

    float h[HID];
    #pragma unroll
    for (int j = 0; j < HID; ++j) {
        float a = b1s[j];
        #pragma unroll
        for (int k = 0; k < WALK; ++k) a += W1s[j * WALK + k] * p[k];
        h[j] = fmaxf(a, 0.0f);
    }

    #pragma unroll
    for (int j = 0; j < HID; j += 4) {
        float4 o;
        float* op = (float*)&o;
        #pragma unroll
        for (int q = 0; q < 4; ++q) {
            float a = b2s[j + q];
            #pragma unroll
            for (int k = 0; k < HID; ++k) a += W2s[(j + q) * HID + k] * h[k];
            op[q] = a;
        }
        *(float4*)&out[(size_t)n * HID + j] = o;
    }
}

// ---------------- fallback (push) kernels ----------------

__global__ __launch_bounds__(256) void init_push(float* __restrict__ deg,
                                                 float* __restrict__ probs, int N) {
    int i = blockIdx.x * 256 + threadIdx.x;
    if (i < N) {
        deg[i] = 1.0f;
        probs[i] = 1.0f;
        #pragma unroll
        for (int k = 1; k <= WALK; ++k) probs[(size_t)k * N + i] = 0.0f;
    }
}

__global__ __launch_bounds__(256) void deg_push(const int* __restrict__ row,
                                                const float* __restrict__ ew,
                                                float* __restrict__ deg, int E) {
    int e = blockIdx.x * 256 + threadIdx.x;
    if (e < E) atomicAdd(&deg[row[e]], ew[e]);
}

__global__ __launch_bounds__(256) void inv_push(const float* __restrict__ deg,
                                                float* __restrict__ dinv, int N) {
    int i = blockIdx.x * 256 + threadIdx.x;
    if (i < N) dinv[i] = 1.0f / fmaxf(deg[i], 1e-8f);
}

__global__ __launch_bounds__(256) void step_push(const int* __restrict__ ei,
                                                 const float* __restrict__ ew,
                                                 const float* __restrict__ dinv,
                                                 const float* __restrict__ src,
                                                 float* __restrict__ dst,
                                                 int E, int N) {
    int idx = blockIdx.x * 256 + threadIdx.x;
    if (idx < E) {
        int r = ei[idx], c = ei[E + idx];
        atomicAdd(&dst[c], src[r] * ew[idx] * dinv[r]);
    } else if (idx < E + N) {
        int i = idx - E;
        atomicAdd(&dst[i], src[i] * dinv[i]);
    }
}

// ---------------- launch ----------------

extern "C" void kernel_launch(void* const* d_in, const int* in_sizes, int n_in,
                              void* d_out, int out_size, void* d_ws, size_t ws_size,
                              hipStream_t stream) {
    const int*   ei = (const int*)d_in[0];
    const float* ew = (const float*)d_in[2];
    const float* W1 = (const float*)d_in[3];
    const float* b1 = (const float*)d_in[4];
    const float* W2 = (const float*)d_in[5];
    const float* b2 = (const float*)d_in[6];
    const int E = in_sizes[2];
    const int N = out_size / HID;
    float* out = (float*)d_out;

    const int NB  = (N + 255) / 256;
    const int NBE = (E + 255) / 256;
    const int NC  = (N + 1023) / 1024;

    size_t need = ((size_t)2 * E + 21 * (size_t)N + 1024 + 32) * 4;
    if (ws_size >= need) {
        char* p = (char*)d_ws;
        uint2* csr   = (uint2*)p;            p += (size_t)E * 8;
        int*  rowptr = (int*)p;              p += (size_t)(N + 1) * 4;
        int*  wp     = (int*)p;              p += (size_t)N * 4;
        int*  bsum   = (int*)p;              p += 1024 * 4;
        float* dinv  = (float*)p;            p += (size_t)N * 4;
        float* probs = (float*)p;            // 18N region: probs|qA|qB
        float* qA    = probs + (size_t)16 * N;
        float* qB    = qA + N;
        // build-time overlays (dead before steps write probs)
        int*   cntx  = (int*)probs;                      // 8N ints
        float* degx  = probs + (size_t)8 * N;            // 8N floats

        hipMemsetAsync(probs, 0, (size_t)16 * N * 4, stream);  // zero cntx+degx
        hist2<<<NBE, 256, 0, stream>>>(ei, ew, cntx, degx, N, E);
        degred<<<NB, 256, 0, stream>>>(cntx, degx, wp, dinv, qA, N);
        scan_a<<<NC, 1024, 0, stream>>>(wp, rowptr, bsum, N);
        scan_b<<<1, 1024, 0, stream>>>(bsum, NC);
        scan_c2<<<NC, 1024, 0, stream>>>(rowptr, cntx, bsum, N, E);
        scatter2<<<NBE, 256, 0, stream>>>(ei, ew, cntx, csr, N, E);

        const int NBW = (N * 64 + 255) / 256;   // one wave per node
        float* qs = qA; float* qd = qB;
        for (int k = 0; k < WALK; ++k) {
            step_pull<<<NBW, 256, 0, stream>>>(rowptr, csr, qs, dinv,
                                               probs + (size_t)k * N, qd, N);
            float* t = qs; qs = qd; qd = t;
        }
        mlp_kernel<<<NB, 256, 0, stream>>>(probs, W1, b1, W2, b2, out, N);
    } else {
        // fallback: push path (3N + 17N ws)
        float* deg   = (float*)d_ws;
        float* dinv  = deg + N;
        float* probs = dinv + N;
        init_push<<<NB, 256, 0, stream>>>(deg, probs, N);
        deg_push<<<NBE, 256, 0, stream>>>(ei, ew, deg, E);
        inv_push<<<NB, 256, 0, stream>>>(deg, dinv, N);
        for (int k = 0; k < WALK; ++k) {
            step_push<<<(E + N + 255) / 256, 256, 0, stream>>>(
                ei, ew, dinv, probs + (size_t)k * N, probs + (size_t)(k + 1) * N, E, N);
        }
        mlp_kernel<<<NB, 256, 0, stream>>>(probs + N, W1, b1, W2, b2, out, N);
    }
}

// Round 4
// 1329.563 us; speedup vs baseline: 4.3541x; 1.3779x over previous
//
#include <hip/hip_runtime.h>

#define WALK 16
#define HID 64
#define CHUNK 16384
#define MAXBKT 1600   // buckets of 64 nodes: supports N <= 102400

// ===========================================================================
// Atomic-free CSR build (counting sort into 64-col buckets) + LDS-accumulated
// pull steps. Global atomics on gfx950 execute at the fabric (~20 G/s)
// regardless of requested scope (R3 measured: WRITE_SIZE 400MB unchanged with
// workgroup scope) — so the build uses LDS atomics + exact-position scans
// only. deg (row side) uses the same machinery when ws allows (tier A), else
// one fabric atomic per edge (tier B).
//
// ws layout (words):
//   csr    : 2E          uint2 {row | col_low<<25, ew_bits}, grouped by bucket
//   degp   : E           (tier A only) (ew_bits & ~63) | row_low, by row-bucket
//   bptrc  : NBKT+1      col-bucket start offsets
//   totc   : NBKT
//   bptrr  : NBKT+1      (tier A)
//   totr   : NBKT        (tier A)
//   dinv   : N
//   qA,qB  : N each      q = prob * dinv (qB = deg scratch in tier B)
//   probs  : 16N         plane k = prob after step k+1
//            overlay during build: Cc[NW*NBKT] (+Cr tier A) counts matrices
// ===========================================================================

// ---- per-chunk LDS histogram -> plain-stored counts matrix C[w*NBKT+b] ----
__global__ __launch_bounds__(256) void hist_k(const int* __restrict__ ei,
                                              int* __restrict__ Cc,
                                              int* __restrict__ Cr,
                                              int NBKT, int E, int do_row) {
    __shared__ int cntc[MAXBKT];
    __shared__ int cntr[MAXBKT];
    int w = blockIdx.x, tid = threadIdx.x;
    for (int b = tid; b < NBKT; b += 256) { cntc[b] = 0; cntr[b] = 0; }
    __syncthreads();
    int s = w * CHUNK;
    int cnt = min(E - s, CHUNK);
    const int* colp = ei + E;
    int vec = ((E & 3) == 0) ? (cnt & ~3) : 0;   // int4 path needs (ei+E) aligned
    for (int off = 4 * tid; off < vec; off += 1024) {
        int4 c4 = *(const int4*)(colp + s + off);
        atomicAdd(&cntc[c4.x >> 6], 1);
        atomicAdd(&cntc[c4.y >> 6], 1);
        atomicAdd(&cntc[c4.z >> 6], 1);
        atomicAdd(&cntc[c4.w >> 6], 1);
        if (do_row) {
            int4 r4 = *(const int4*)(ei + s + off);
            atomicAdd(&cntr[r4.x >> 6], 1);
            atomicAdd(&cntr[r4.y >> 6], 1);
            atomicAdd(&cntr[r4.z >> 6], 1);
            atomicAdd(&cntr[r4.w >> 6], 1);
        }
    }
    for (int off = vec + tid; off < cnt; off += 256) {
        atomicAdd(&cntc[colp[s + off] >> 6], 1);
        if (do_row) atomicAdd(&cntr[ei[s + off] >> 6], 1);
    }
    __syncthreads();
    for (int b = tid; b < NBKT; b += 256) {
        Cc[(size_t)w * NBKT + b] = cntc[b];
        if (do_row) Cr[(size_t)w * NBKT + b] = cntr[b];
    }
}

// ---- per-bucket prefix over chunks (in place); tot[b] = bucket total ----
__global__ __launch_bounds__(256) void colscan_k(int* __restrict__ C,
                                                 int* __restrict__ tot,
                                                 int NBKT, int NW) {
    int b = blockIdx.x * 256 + threadIdx.x;
    if (b >= NBKT) return;
    int run = 0;
    for (int w = 0; w < NW; ++w) {
        size_t idx = (size_t)w * NBKT + b;
        int t = C[idx];
        C[idx] = run;
        run += t;
    }
    tot[b] = run;
}

// ---- single-wg exclusive scan of bucket totals -> bptr; bptr[NBKT] = E ----
__global__ __launch_bounds__(1024) void bktscan_k(const int* __restrict__ tot,
                                                  int* __restrict__ ptr,
                                                  int NBKT, int E) {
    __shared__ int wsum[16];
    __shared__ int carry_s;
    int tid = threadIdx.x, lane = tid & 63, wid = tid >> 6;
    if (tid == 0) carry_s = 0;
    __syncthreads();
    for (int base = 0; base < NBKT; base += 1024) {
        int x = (base + tid < NBKT) ? tot[base + tid] : 0;
        int v = x;
        #pragma unroll
        for (int d = 1; d < 64; d <<= 1) { int t = __shfl_up(v, d); if (lane >= d) v += t; }
        __syncthreads();                  // protect wsum from prev iteration
        if (lane == 63) wsum[wid] = v;
        __syncthreads();
        if (tid < 16) {
            int sv = wsum[tid];
            #pragma unroll
            for (int d = 1; d < 16; d <<= 1) { int t = __shfl_up(sv, d); if (tid >= d) sv += t; }
            wsum[tid] = sv;
        }
        __syncthreads();
        int woff = wid ? wsum[wid - 1] : 0;
        int carry = carry_s;
        if (base + tid < NBKT) ptr[base + tid] = carry + woff + v - x;
        __syncthreads();
        if (tid == 0) carry_s = carry + wsum[15];
    }
    if (tid == 0) ptr[NBKT] = E;
}

// ---- scatter edges to exact positions; cursors are LDS return-atomics ----
__global__ __launch_bounds__(256) void scatter_k(const int* __restrict__ ei,
                                                 const float* __restrict__ ew,
                                                 const int* __restrict__ Cc,
                                                 const int* __restrict__ Cr,
                                                 const int* __restrict__ bptrc,
                                                 const int* __restrict__ bptrr,
                                                 uint2* __restrict__ csr,
                                                 unsigned* __restrict__ degp,
                                                 int NBKT, int E, int do_row) {
    __shared__ int basec[MAXBKT], curc[MAXBKT];
    __shared__ int baser[MAXBKT], curr[MAXBKT];
    int w = blockIdx.x, tid = threadIdx.x;
    for (int b = tid; b < NBKT; b += 256) {
        basec[b] = bptrc[b] + Cc[(size_t)w * NBKT + b];
        curc[b] = 0;
        if (do_row) {
            baser[b] = bptrr[b] + Cr[(size_t)w * NBKT + b];
            curr[b] = 0;
        }
    }
    __syncthreads();
    int s = w * CHUNK;
    int e_end = min(E, s + CHUNK);
    for (int e = s + tid; e < e_end; e += 256) {
        int r = ei[e], c = ei[E + e];
        unsigned wb = __float_as_uint(ew[e]);
        int bc = c >> 6;
        int l = atomicAdd(&curc[bc], 1);
        csr[basec[bc] + l] = make_uint2((unsigned)r | ((unsigned)(c & 63) << 25), wb);
        if (do_row) {
            int br = r >> 6;
            int l2 = atomicAdd(&curr[br], 1);
            degp[baser[br] + l2] = (wb & ~63u) | (unsigned)(r & 63);
        }
    }
}

// ---- deg via LDS accumulation over row-buckets (tier A) ----
__global__ __launch_bounds__(256) void deg_k(const unsigned* __restrict__ degp,
                                             const int* __restrict__ bptrr,
                                             float* __restrict__ dinv,
                                             float* __restrict__ q0, int N) {
    __shared__ float acc[64];
    int rb = blockIdx.x, tid = threadIdx.x;
    if (tid < 64) acc[tid] = 0.0f;
    __syncthreads();
    int s = bptrr[rb], e = bptrr[rb + 1];
    int i = s + tid;
    for (; i + 768 < e; i += 1024) {
        unsigned p0 = degp[i], p1 = degp[i + 256], p2 = degp[i + 512], p3 = degp[i + 768];
        atomicAdd(&acc[p0 & 63], __uint_as_float(p0 & ~63u));
        atomicAdd(&acc[p1 & 63], __uint_as_float(p1 & ~63u));
        atomicAdd(&acc[p2 & 63], __uint_as_float(p2 & ~63u));
        atomicAdd(&acc[p3 & 63], __uint_as_float(p3 & ~63u));
    }
    for (; i < e; i += 256) {
        unsigned p = degp[i];
        atomicAdd(&acc[p & 63], __uint_as_float(p & ~63u));
    }
    __syncthreads();
    if (tid < 64) {
        int r = rb * 64 + tid;
        if (r < N) {
            float dv = 1.0f / fmaxf(acc[tid] + 1.0f, 1e-8f);  // +1 self-loop
            dinv[r] = dv;
            q0[r] = dv;   // q = prob*dinv, prob0 = 1
        }
    }
}

// ---- tier B deg: fabric atomics + inverse ----
__global__ __launch_bounds__(256) void dega_k(const int* __restrict__ ei,
                                              const float* __restrict__ ew,
                                              float* __restrict__ deg, int E) {
    int e = blockIdx.x * 256 + threadIdx.x;
    if (e < E) atomicAdd(&deg[ei[e]], ew[e]);
}

__global__ __launch_bounds__(256) void inv_k(const float* __restrict__ deg,
                                             float* __restrict__ dinv,
                                             float* __restrict__ q0, int N) {
    int i = blockIdx.x * 256 + threadIdx.x;
    if (i < N) {
        float dv = 1.0f / fmaxf(deg[i] + 1.0f, 1e-8f);
        dinv[i] = dv;
        q0[i] = dv;
    }
}

// ---- one step: per col-bucket LDS accumulate, no global atomics ----
__global__ __launch_bounds__(256) void step_k(const uint2* __restrict__ csr,
                                              const int* __restrict__ bptrc,
                                              const float* __restrict__ q,
                                              const float* __restrict__ dinv,
                                              float* __restrict__ prob_out,
                                              float* __restrict__ q_out, int N) {
    __shared__ float acc[64];
    int cb = blockIdx.x, tid = threadIdx.x;
    if (tid < 64) acc[tid] = 0.0f;
    __syncthreads();
    int s = bptrc[cb], e = bptrc[cb + 1];
    int i = s + tid;
    for (; i + 768 < e; i += 1024) {   // 4-deep pipeline: 4 csr loads, 4 gathers in flight
        uint2 t0 = csr[i], t1 = csr[i + 256], t2 = csr[i + 512], t3 = csr[i + 768];
        float v0 = q[t0.x & 0x1FFFFFF] * __uint_as_float(t0.y);
        float v1 = q[t1.x & 0x1FFFFFF] * __uint_as_float(t1.y);
        float v2 = q[t2.x & 0x1FFFFFF] * __uint_as_float(t2.y);
        float v3 = q[t3.x & 0x1FFFFFF] * __uint_as_float(t3.y);
        atomicAdd(&acc[t0.x >> 25], v0);
        atomicAdd(&acc[t1.x >> 25], v1);
        atomicAdd(&acc[t2.x >> 25], v2);
        atomicAdd(&acc[t3.x >> 25], v3);
    }
    for (; i < e; i += 256) {
        uint2 t = csr[i];
        atomicAdd(&acc[t.x >> 25], q[t.x & 0x1FFFFFF] * __uint_as_float(t.y));
    }
    __syncthreads();
    if (tid < 64) {
        int c = cb * 64 + tid;
        if (c < N) {
            float p = acc[tid] + q[c];   // self-loop: prob[c]*dinv[c] = q[c]
            prob_out[c] = p;
            q_out[c] = p * dinv[c];
        }
    }
}

// ---- per-node MLP ----
__global__ __launch_bounds__(256) void mlp_kernel(const float* __restrict__ probs,
                                                  const float* __restrict__ W1,
                                                  const float* __restrict__ b1,
                                                  const float* __restrict__ W2,
                                                  const float* __restrict__ b2,
                                                  float* __restrict__ out, int N) {
    __shared__ float W1s[HID * WALK];
    __shared__ float W2s[HID * HID];
    __shared__ float b1s[HID], b2s[HID];
    int tid = threadIdx.x;
    for (int i = tid; i < HID * WALK; i += 256) W1s[i] = W1[i];
    for (int i = tid; i < HID * HID; i += 256) W2s[i] = W2[i];
    if (tid < HID) { b1s[tid] = b1[tid]; b2s[tid] = b2[tid]; }
    __syncthreads();

    int n = blockIdx.x * 256 + tid;
    if (n >= N) return;

    float p[WALK];
    #pragma unroll
    for (int k = 0; k < WALK; ++k) p[k] = probs[(size_t)k * N + n];

    float h[HID];
    #pragma unroll
    for (int j = 0; j < HID; ++j) {
        float a = b1s[j];
        #pragma unroll
        for (int k = 0; k < WALK; ++k) a += W1s[j * WALK + k] * p[k];
        h[j] = fmaxf(a, 0.0f);
    }

    #pragma unroll
    for (int j = 0; j < HID; j += 4) {
        float4 o;
        float* op = (float*)&o;
        #pragma unroll
        for (int qq = 0; qq < 4; ++qq) {
            float a = b2s[j + qq];
            #pragma unroll
            for (int k = 0; k < HID; ++k) a += W2s[(j + qq) * HID + k] * h[k];
            op[qq] = a;
        }
        *(float4*)&out[(size_t)n * HID + j] = o;
    }
}

// ---- last-resort push fallback ----
__global__ __launch_bounds__(256) void init_push(float* __restrict__ probs, int N) {
    int i = blockIdx.x * 256 + threadIdx.x;
    if (i < N) {
        probs[i] = 1.0f;
        #pragma unroll
        for (int k = 1; k <= WALK; ++k) probs[(size_t)k * N + i] = 0.0f;
    }
}

__global__ __launch_bounds__(256) void step_push(const int* __restrict__ ei,
                                                 const float* __restrict__ ew,
                                                 const float* __restrict__ dinv,
                                                 const float* __restrict__ src,
                                                 float* __restrict__ dst,
                                                 int E, int N) {
    int idx = blockIdx.x * 256 + threadIdx.x;
    if (idx < E) {
        int r = ei[idx], c = ei[E + idx];
        atomicAdd(&dst[c], src[r] * ew[idx] * dinv[r]);
    } else if (idx < E + N) {
        int i = idx - E;
        atomicAdd(&dst[i], src[i] * dinv[i]);
    }
}

// ---- launch ----
extern "C" void kernel_launch(void* const* d_in, const int* in_sizes, int n_in,
                              void* d_out, int out_size, void* d_ws, size_t ws_size,
                              hipStream_t stream) {
    const int*   ei = (const int*)d_in[0];
    const float* ew = (const float*)d_in[2];
    const float* W1 = (const float*)d_in[3];
    const float* b1 = (const float*)d_in[4];
    const float* W2 = (const float*)d_in[5];
    const float* b2 = (const float*)d_in[6];
    const int E = in_sizes[2];
    const int N = out_size / HID;
    float* out = (float*)d_out;

    const int NB   = (N + 255) / 256;
    const int NBKT = (N + 63) / 64;
    const int NW   = (E + CHUNK - 1) / CHUNK;

    // word budgets
    size_t wordsB = (size_t)2 * E + 2 * (size_t)NBKT + 1 + 19 * (size_t)N + 64;
    size_t wordsA = wordsB + (size_t)E + 2 * (size_t)NBKT + 1;
    bool overlay_ok = (size_t)2 * NW * NBKT <= (size_t)16 * N;
    bool okA = NBKT <= MAXBKT && overlay_ok && ws_size >= wordsA * 4;
    bool okB = NBKT <= MAXBKT && ((size_t)NW * NBKT <= (size_t)16 * N) && ws_size >= wordsB * 4;

    if (okA || okB) {
        char* p = (char*)d_ws;
        uint2* csr = (uint2*)p;              p += (size_t)E * 8;
        unsigned* degp = nullptr;
        if (okA) { degp = (unsigned*)p;      p += (size_t)E * 4; }
        int* bptrc = (int*)p;                p += (size_t)(NBKT + 1) * 4;
        int* totc  = (int*)p;                p += (size_t)NBKT * 4;
        int* bptrr = nullptr; int* totr = nullptr;
        if (okA) {
            bptrr = (int*)p;                 p += (size_t)(NBKT + 1) * 4;
            totr  = (int*)p;                 p += (size_t)NBKT * 4;
        }
        float* dinv = (float*)p;             p += (size_t)N * 4;
        float* qA   = (float*)p;             p += (size_t)N * 4;
        float* qB   = (float*)p;             p += (size_t)N * 4;
        float* probs = (float*)p;
        int* Cc = (int*)probs;                         // overlay, dead before steps
        int* Cr = Cc + (size_t)NW * NBKT;

        hist_k<<<NW, 256, 0, stream>>>(ei, Cc, Cr, NBKT, E, okA ? 1 : 0);
        colscan_k<<<(NBKT + 255) / 256, 256, 0, stream>>>(Cc, totc, NBKT, NW);
        bktscan_k<<<1, 1024, 0, stream>>>(totc, bptrc, NBKT, E);
        if (okA) {
            colscan_k<<<(NBKT + 255) / 256, 256, 0, stream>>>(Cr, totr, NBKT, NW);
            bktscan_k<<<1, 1024, 0, stream>>>(totr, bptrr, NBKT, E);
        }
        scatter_k<<<NW, 256, 0, stream>>>(ei, ew, Cc, Cr, bptrc, bptrr, csr, degp,
                                          NBKT, E, okA ? 1 : 0);
        if (okA) {
            deg_k<<<NBKT, 256, 0, stream>>>(degp, bptrr, dinv, qA, N);
        } else {
            hipMemsetAsync(qB, 0, (size_t)N * 4, stream);   // qB doubles as deg
            dega_k<<<(E + 255) / 256, 256, 0, stream>>>(ei, ew, qB, E);
            inv_k<<<NB, 256, 0, stream>>>(qB, dinv, qA, N);
        }

        float* qs = qA; float* qd = qB;
        for (int k = 0; k < WALK; ++k) {
            step_k<<<NBKT, 256, 0, stream>>>(csr, bptrc, qs, dinv,
                                             probs + (size_t)k * N, qd, N);
            float* t = qs; qs = qd; qd = t;
        }
        mlp_kernel<<<NB, 256, 0, stream>>>(probs, W1, b1, W2, b2, out, N);
    } else {
        // push fallback: deg in ws[0..N), dinv next, probs 17N after
        float* deg   = (float*)d_ws;
        float* dinv  = deg + N;
        float* probs = dinv + N;
        hipMemsetAsync(deg, 0, (size_t)N * 4, stream);
        init_push<<<NB, 256, 0, stream>>>(probs, N);
        dega_k<<<(E + 255) / 256, 256, 0, stream>>>(ei, ew, deg, E);
        inv_k<<<NB, 256, 0, stream>>>(deg, dinv, dinv, N);  // dinv only (q0 unused)
        for (int k = 0; k < WALK; ++k) {
            step_push<<<(E + N + 255) / 256, 256, 0, stream>>>(
                ei, ew, dinv, probs + (size_t)k * N, probs + (size_t)(k + 1) * N, E, N);
        }
        mlp_kernel<<<NB, 256, 0, stream>>>(probs + N, W1, b1, W2, b2, out, N);
    }
}